// Round 13
// baseline (175.408 us; speedup 1.0000x reference)
//
#include <hip/hip_runtime.h>
#include <cstddef>
#include <cstdint>

// Problem constants (fixed by setup_inputs).
#define E_ 1024
#define H_ 16
#define HD_ 64
#define B_ 2
#define S_ 1024
#define NSEG 64
#define SEGLEN (S_/NSEG)          // 16
#define CHUNKS 64
#define CHLEN (S_/CHUNKS)         // 16
#define SCALE 0.03125f            // 1/sqrt(E)

typedef __attribute__((ext_vector_type(8))) short bf16x8;
typedef __attribute__((ext_vector_type(4))) float f32x4;

__device__ __forceinline__ unsigned short f2bf_rne(float x) {
  uint32_t u = __float_as_uint(x);
  uint32_t r = u + 0x7FFFu + ((u >> 16) & 1u);
  return (unsigned short)(r >> 16);
}
__device__ __forceinline__ float bf2f(unsigned short h) {
  return __uint_as_float(((uint32_t)h) << 16);
}
__device__ __forceinline__ void gload_lds16(const void* g, void* l) {
  __builtin_amdgcn_global_load_lds(
      (const __attribute__((address_space(1))) void*)g,
      (__attribute__((address_space(3))) void*)l, 16, 0, 0);
}

// ========== P1: independent prep (kA | kC | kD | k1 | bias-init) ==========
// [0,512): kA_segsum          [512,2560): kC_split_q (hi only)
// [2560,4608): kD_splitW (hi) [4608,5120): k1_colsum  [5120,5136): init
__global__ __launch_bounds__(256) void kP1(
    const float* __restrict__ query, const float* __restrict__ pos,
    const float* __restrict__ key,   const float* __restrict__ value,
    const float* __restrict__ Wq,    const float* __restrict__ Wp,
    const float* __restrict__ bk,    const float* __restrict__ bv,
    float* __restrict__ seg, unsigned short* __restrict__ Aq,
    float* __restrict__ pk, float* __restrict__ pv,
    unsigned short* __restrict__ Btq, unsigned short* __restrict__ Btp,
    float* __restrict__ ksum, float* __restrict__ vsum) {
  __shared__ float tile[32][33];
  int bid = blockIdx.x;
  int t = threadIdx.x;
  if (bid < 512) {
    // ---- kA: per-segment sums of pos ----
    int idx = bid*256 + t;
    int e = idx % E_;
    int g = (idx / E_) % NSEG;
    int b = idx / (E_*NSEG);
    const float* p = pos + ((size_t)(b*S_ + g*SEGLEN))*E_ + e;
    float s = 0.f;
    #pragma unroll
    for (int i = 0; i < SEGLEN; ++i) s += p[(size_t)i*E_];
    seg[(b*NSEG + g)*E_ + e] = s;
  } else if (bid < 2560) {
    // ---- kC: query -> bf16 hi only, A'q = [2048][1024] ----
    int idx = (bid-512)*256 + t;
    int e4 = idx & 255;
    int r  = idx >> 8;
    float4 v = ((const float4*)query)[idx];
    ushort4 hi;
    hi.x = f2bf_rne(v.x); hi.y = f2bf_rne(v.y);
    hi.z = f2bf_rne(v.z); hi.w = f2bf_rne(v.w);
    *(ushort4*)&Aq[(size_t)r*1024 + e4*4] = hi;
  } else if (bid < 4608) {
    // ---- kD: transpose Wq/Wp -> B'T hi only, [1024][1024] ----
    int f = bid - 2560;
    int nt = f & 31, kt = (f >> 5) & 31, z = f >> 10;
    const float* W = z ? Wp : Wq;
    unsigned short* Bt = z ? Btp : Btq;
    int lr = t >> 3;
    int lc = (t & 7) * 4;
    float4 v = *(const float4*)&W[(size_t)(kt*32 + lr)*E_ + nt*32 + lc];
    tile[lr][lc+0] = v.x; tile[lr][lc+1] = v.y;
    tile[lr][lc+2] = v.z; tile[lr][lc+3] = v.w;
    __syncthreads();
    int n = nt*32 + lr;
    ushort4 hi;
    hi.x = f2bf_rne(tile[lc+0][lr]); hi.y = f2bf_rne(tile[lc+1][lr]);
    hi.z = f2bf_rne(tile[lc+2][lr]); hi.w = f2bf_rne(tile[lc+3][lr]);
    *(ushort4*)&Bt[(size_t)n*1024 + kt*32 + lc] = hi;
  } else if (bid < 5120) {
    // ---- k1: partial column sums of key and value ----
    int idx = (bid-4608)*256 + t;
    int e = idx % E_;
    int c = (idx / E_) % CHUNKS;
    int b = idx / (E_*CHUNKS);
    const float* kp = key   + ((size_t)(b*S_ + c*CHLEN))*E_ + e;
    const float* vp = value + ((size_t)(b*S_ + c*CHLEN))*E_ + e;
    float sk = 0.f, sv = 0.f;
    #pragma unroll
    for (int s = 0; s < CHLEN; ++s) {
      sk += kp[(size_t)s*E_];
      sv += vp[(size_t)s*E_];
    }
    pk[(b*CHUNKS + c)*E_ + e] = sk;
    pv[(b*CHUNKS + c)*E_ + e] = sv;
  } else {
    // ---- init: ksum/vsum = S*bias (atomics accumulate on top in kP2) ----
    int idx = (bid-5120)*256 + t;   // 0..4095
    int e = idx & 1023;
    int b = (idx >> 10) & 1;
    int j = idx >> 11;
    (j ? vsum : ksum)[b*E_ + e] = (float)S_ * (j ? bv : bk)[e];
  }
}

// ======== P2: kB scan+split | fused colsum+GEMV (atomic ksum/vsum) ========
// [0,512): kB   [512,544): one block per (j, 64-row e-slice)
__global__ __launch_bounds__(256) void kP2(
    const float* __restrict__ pos, const float* __restrict__ seg,
    unsigned short* __restrict__ Ap,
    const float* __restrict__ pk, const float* __restrict__ pv,
    const float* __restrict__ Wk, const float* __restrict__ Wv,
    float* __restrict__ ksum, float* __restrict__ vsum) {
  int bid = blockIdx.x;
  int t = threadIdx.x;
  if (bid < 512) {
    // ---- kB: inclusive prefix-scan of pos, fused split-bf16 write ----
    int idx = bid*256 + t;
    int e = idx % E_;
    int g = (idx / E_) % NSEG;
    int b = idx / (E_*NSEG);
    float run = 0.f;
    for (int gp = 0; gp < g; ++gp) run += seg[(b*NSEG + gp)*E_ + e];
    const float* p = pos + ((size_t)(b*S_ + g*SEGLEN))*E_ + e;
    #pragma unroll
    for (int i = 0; i < SEGLEN; ++i) {
      run += p[(size_t)i*E_];
      size_t row = (size_t)(b*S_ + g*SEGLEN + i);
      unsigned short hb = f2bf_rne(run);
      float lf = run - bf2f(hb);
      Ap[row*2048 + e]        = hb;
      Ap[row*2048 + 1024 + e] = f2bf_rne(lf);
    }
  } else {
    // ---- fused: recompute 64-e-slice colsums from pk/pv, then GEMV ----
    __shared__ float csL[2][64];
    int f = bid - 512;             // 0..31
    int j     = f >> 4;            // 0: key, 1: value
    int slice = f & 15;
    int e0 = slice*64;
    const float* p = j ? pv : pk;
    int pair = t >> 1;             // 0..127 -> (b, el)
    int half = t & 1;
    int b  = pair >> 6;
    int el = pair & 63;
    float s = 0.f;
    #pragma unroll 8
    for (int c = half*32; c < half*32 + 32; ++c)
      s += p[(size_t)(b*CHUNKS + c)*E_ + e0 + el];
    s += __shfl_xor(s, 1);
    if (half == 0) csL[b][el] = s;
    __syncthreads();
    const float* W = j ? Wv : Wk;
    float* outp = j ? vsum : ksum;
    #pragma unroll
    for (int i = 0; i < 4; ++i) {
      int n = i*256 + t;
      float a0 = 0.f, a1 = 0.f;
      #pragma unroll 8
      for (int e = 0; e < 64; ++e) {
        float w = W[(size_t)(e0 + e)*E_ + n];
        a0 += csL[0][e] * w;
        a1 += csL[1][e] * w;
      }
      atomicAdd(&outp[n], a0);
      atomicAdd(&outp[E_ + n], a1);
    }
  }
}

// ========== P4: kG MFMA GEMM (512 blocks) | k3 (128 blocks) ==========
// z=0: Cq = query @ Wq + bq  (1-product: Ah*Bh, 16 k-tiles)
// z=1: Cp = prefix(pos) @ Wp (2-product: Ah*Bh + Al*Bh, 32 k-tiles)
__global__ __launch_bounds__(256, 2) void kP4(
    const unsigned short* __restrict__ Aq, const unsigned short* __restrict__ Btq,
    const float* __restrict__ bq,
    const unsigned short* __restrict__ Ap, const unsigned short* __restrict__ Btp,
    float* __restrict__ Cq, float* __restrict__ Cp,
    const float* __restrict__ vsum, const float* __restrict__ Wo,
    float* __restrict__ WV) {
  __shared__ __align__(128) char lds[49152];
  int bid = blockIdx.x;
  const int t = threadIdx.x;
  if (bid >= 512) {
    // ---- k3: WV[b,h,n] = vsum[b,h*64+d] dot Wo ----
    int idx = (bid-512)*256 + t;
    int n = idx % E_;
    int h = (idx / E_) % H_;
    int b = idx / (E_*H_);
    float acc = 0.f;
    #pragma unroll 8
    for (int d = 0; d < HD_; ++d)
      acc += vsum[b*E_ + h*HD_ + d] * Wo[(size_t)(h*HD_ + d)*E_ + n];
    WV[idx] = acc;
    return;
  }
  // ---- kG: z-balanced XCD-aware bijective swizzle over 512 blocks ----
  // Each XCD gets 32 z=0 + 32 z=1 blocks (2 bm-panels per z) so the
  // 2x-heavier z=1 work is spread evenly (round-12 swizzle put all z=1
  // on XCDs 4-7: 64 vs 32 tile-units per CU; this one gives 48 evenly).
  int wg = bid;
  int xcd = wg & 7;
  int i   = wg >> 3;             // 0..63
  int newid = (i < 32) ? (xcd*32 + i) : (256 + xcd*32 + (i - 32));
  int z  = newid >> 8;
  int bm = (newid >> 4) & 15;
  int bn = newid & 15;
  const int lane = t & 63;
  const int wm = (t >> 6) >> 1;
  const int wn = (t >> 6) & 1;

  const unsigned short* A; const unsigned short* Bt;
  const float* bias; float* C;
  int alen, ntot;
  if (z == 0) { A = Aq; Bt = Btq; bias = bq;      C = Cq; alen = 1024; ntot = 16; }
  else        { A = Ap; Bt = Btp; bias = nullptr; C = Cp; alen = 2048; ntot = 32; }

  // Pre-swizzled global source addresses (rule 21).
  const unsigned short* asrc[4];
  const unsigned short* bsrc[2];
  #pragma unroll
  for (int i2 = 0; i2 < 4; ++i2) {
    int L = i2*4096 + t*16;
    int row = L >> 7, bir = L & 127;
    int sw = bir ^ ((row & 7) << 4);
    asrc[i2] = A + (size_t)(bm*128 + row)*alen + (sw >> 1);
  }
  #pragma unroll
  for (int i2 = 0; i2 < 2; ++i2) {
    int L = i2*4096 + t*16;
    int row = L >> 7, bir = L & 127;
    int sw = bir ^ ((row & 7) << 4);
    bsrc[i2] = Bt + (size_t)(bn*64 + row)*1024 + (sw >> 1);
  }
  int aoff[2][4], boff[2][2];
  #pragma unroll
  for (int ks = 0; ks < 2; ++ks) {
    int k0b = (ks*32 + (lane >> 4)*8) * 2;
    #pragma unroll
    for (int mi = 0; mi < 4; ++mi) {
      int row = wm*64 + mi*16 + (lane & 15);
      aoff[ks][mi] = row*128 + (k0b ^ ((row & 7) << 4));
    }
    #pragma unroll
    for (int ni = 0; ni < 2; ++ni) {
      int rown = wn*32 + ni*16 + (lane & 15);
      boff[ks][ni] = rown*128 + (k0b ^ ((rown & 7) << 4));
    }
  }

  f32x4 acc[4][2] = {};

  auto stage = [&](int buf, int kt) {
    int ak = kt;                           // z=0: [0,16) hi; z=1: [0,32) hi|lo
    int bk = (kt < 16) ? kt : kt - 16;     // B always hi
    char* Ab = lds + buf*16384;
    char* Bb = lds + 32768 + buf*8192;
    #pragma unroll
    for (int i2 = 0; i2 < 4; ++i2)
      gload_lds16(asrc[i2] + ak*64, Ab + i2*4096 + t*16);
    #pragma unroll
    for (int i2 = 0; i2 < 2; ++i2)
      gload_lds16(bsrc[i2] + bk*64, Bb + i2*4096 + t*16);
  };

  stage(0, 0);
  __syncthreads();
  int cur = 0;
  for (int kt = 0; kt < ntot; ++kt) {
    if (kt + 1 < ntot) stage(cur ^ 1, kt + 1);
    const char* Ab = lds + cur*16384;
    const char* Bb = lds + 32768 + cur*8192;
    bf16x8 af[2][4], bf_[2][2];
    #pragma unroll
    for (int ks = 0; ks < 2; ++ks) {
      #pragma unroll
      for (int mi = 0; mi < 4; ++mi)
        af[ks][mi] = *(const bf16x8*)(Ab + aoff[ks][mi]);
      #pragma unroll
      for (int ni = 0; ni < 2; ++ni)
        bf_[ks][ni] = *(const bf16x8*)(Bb + boff[ks][ni]);
    }
    #pragma unroll
    for (int ks = 0; ks < 2; ++ks)
      #pragma unroll
      for (int mi = 0; mi < 4; ++mi)
        #pragma unroll
        for (int ni = 0; ni < 2; ++ni)
          acc[mi][ni] = __builtin_amdgcn_mfma_f32_16x16x32_bf16(
              af[ks][mi], bf_[ks][ni], acc[mi][ni], 0, 0, 0);
    __syncthreads();
    cur ^= 1;
  }

  #pragma unroll
  for (int mi = 0; mi < 4; ++mi) {
    #pragma unroll
    for (int ni = 0; ni < 2; ++ni) {
      int col  = bn*64 + wn*32 + ni*16 + (lane & 15);
      int row0 = bm*128 + wm*64 + mi*16 + (lane >> 4)*4;
      float badd = bias ? bias[col] : 0.f;
      #pragma unroll
      for (int j = 0; j < 4; ++j)
        C[(size_t)(row0 + j)*E_ + col] = acc[mi][ni][j] + badd;
    }
  }
}

// ===== kFin: fused k6 (row-sums) + k7 (out GEMV). One block per (b,q). =====
__global__ __launch_bounds__(256) void kFin(
    const float* __restrict__ qp, const float* __restrict__ Rpre,
    const float* __restrict__ ksum, const float* __restrict__ U,
    const float* __restrict__ V, const float* __restrict__ WV,
    const float* __restrict__ bo, float* __restrict__ out) {
  __shared__ float rsL[H_];
  int bq = blockIdx.x;
  int b = bq >> 10, q = bq & 1023;
  int t = threadIdx.x;
  int w = t >> 6, lane = t & 63;
  const float* qrow0 = qp + ((size_t)(b*S_ + q))*E_;
  const float* rt    = Rpre + ((size_t)(b*S_ + (S_-1)))*E_;
  #pragma unroll
  for (int i = 0; i < 4; ++i) {
    int h = w*4 + i;
    int he = h*HD_ + lane;
    float qv0 = qrow0[he];
    float u = U[he], vv = V[he];
    float ks = ksum[b*E_ + he];
    float tail = rt[he];
    if (q <= S_-2) tail -= Rpre[((size_t)(b*S_ + (S_-2-q)))*E_ + he];
    float p = (qv0 + u)*ks + (qv0 + vv)*tail;
    if (q <= S_-3) {
      float qv1 = qrow0[E_ + he];   // row q+1
      p += (qv1 + vv)*Rpre[((size_t)(b*S_ + (S_-3-q)))*E_ + he];
    }
    #pragma unroll
    for (int off = 32; off >= 1; off >>= 1)
      p += __shfl_xor(p, off);
    if (lane == 0) rsL[h] = p * SCALE;
  }
  __syncthreads();
  #pragma unroll
  for (int i = 0; i < 4; ++i) {
    int n = i*256 + t;
    float acc = bo[n];
    #pragma unroll
    for (int h = 0; h < H_; ++h)
      acc += rsL[h] * WV[((size_t)(b*H_ + h))*E_ + n];
    out[((size_t)(b*S_ + q))*E_ + n] = acc;
  }
}

extern "C" void kernel_launch(void* const* d_in, const int* in_sizes, int n_in,
                              void* d_out, int out_size, void* d_ws, size_t ws_size,
                              hipStream_t stream) {
  const float* query = (const float*)d_in[0];
  const float* key   = (const float*)d_in[1];
  const float* value = (const float*)d_in[2];
  const float* pos   = (const float*)d_in[3];
  const float* Wq = (const float*)d_in[4];
  const float* bq = (const float*)d_in[5];
  const float* Wk = (const float*)d_in[6];
  const float* bk = (const float*)d_in[7];
  const float* Wv = (const float*)d_in[8];
  const float* bv = (const float*)d_in[9];
  const float* Wp = (const float*)d_in[10];
  const float* U  = (const float*)d_in[11];
  const float* V  = (const float*)d_in[12];
  const float* Wo = (const float*)d_in[13];
  const float* bo = (const float*)d_in[14];
  float* out = (float*)d_out;
  char* wsb = (char*)d_ws;

  // Peak ~34 MB; qproj in ws (kFin needs d_out free of cross-block hazards).
  unsigned short* Aqs = (unsigned short*)(wsb);                       // 4 MB [2048][1024]
  unsigned short* Aps = (unsigned short*)(wsb + (4ull<<20));          // 8 MB [2048][2048]
  unsigned short* Btq = (unsigned short*)(wsb + (12ull<<20));         // 2 MB [1024][1024]
  unsigned short* Btp = (unsigned short*)(wsb + (14ull<<20));         // 2 MB [1024][1024]
  float* Rpre  = (float*)(wsb + (16ull<<20));                         // 8 MB
  float* qproj = (float*)(wsb + (24ull<<20));                         // 8 MB
  char*  smallb = wsb + (32ull<<20);
  float* seg   = (float*)(smallb);                                    // 512 KB
  float* pk    = (float*)(smallb + (512ull<<10));                     // 512 KB
  float* pv    = (float*)(smallb + (1024ull<<10));                    // 512 KB
  float* ksum  = (float*)(smallb + (1536ull<<10));                    // 8 KB
  float* vsum  = (float*)(smallb + (1544ull<<10));                    // 8 KB
  float* WVb   = (float*)(smallb + (1552ull<<10));                    // 128 KB

  hipLaunchKernelGGL(kP1, dim3(5136), dim3(256), 0, stream,
                     query, pos, key, value, Wq, Wp, bk, bv,
                     seg, Aqs, pk, pv, Btq, Btp, ksum, vsum);
  hipLaunchKernelGGL(kP2, dim3(544), dim3(256), 0, stream,
                     pos, seg, Aps, pk, pv, Wk, Wv, ksum, vsum);
  hipLaunchKernelGGL(kP4, dim3(640), dim3(256), 0, stream,
                     Aqs, Btq, bq, Aps, Btp, qproj, Rpre, vsum, Wo, WVb);
  hipLaunchKernelGGL(kFin, dim3(B_*S_), dim3(256), 0, stream,
                     qproj, Rpre, ksum, U, V, WVb, bo, out);
}